// Round 9
// baseline (1229.146 us; speedup 1.0000x reference)
//
#include <hip/hip_runtime.h>

typedef unsigned int uint;
typedef unsigned short ushort;

typedef __attribute__((ext_vector_type(8))) short sh8;
typedef __attribute__((ext_vector_type(4))) float f32x4;

__device__ __forceinline__ ushort f2b(float f) {
    uint x = __float_as_uint(f);
    x += 0x7fffu + ((x >> 16) & 1u);
    return (ushort)(x >> 16);
}
__device__ __forceinline__ float b2f(ushort u) {
    return __uint_as_float(((uint)u) << 16);
}
__device__ __forceinline__ uint pack2(float a, float b) {
    return (uint)f2b(a) | ((uint)f2b(b) << 16);
}
__device__ __forceinline__ float sigmf(float x) {
    return 1.0f / (1.0f + __expf(-x));
}
__device__ __forceinline__ float tanh_cl(float y) {
    y = fminf(20.0f, fmaxf(-20.0f, y));
    float e = __expf(-2.0f * y);
    return (1.0f - e) / (1.0f + e);
}

// ---------------------------------------------------------------------------
// Index-width detector for x (robustness; x believed int32).
// Samples odd 32-bit words: int64 tokens < 2^31 -> high halves all zero.
// ---------------------------------------------------------------------------
__global__ __launch_bounds__(256) void k_detx(const uint* __restrict__ xw,
                                              int* __restrict__ flag) {
    __shared__ int sh[256];
    int t = threadIdx.x;
    int c = 0;
    for (int i = t; i < 2048; i += 256) c += (xw[2 * i + 1] == 0u) ? 1 : 0;
    sh[t] = c;
    __syncthreads();
    if (t == 0) {
        int s = 0;
        for (int i = 0; i < 256; i++) s += sh[i];
        flag[0] = (s >= 1843) ? 1 : 0;  // >=90% zeros -> int64
    }
}

// ---------------------------------------------------------------------------
// Embedding gather, fp32 -> bf16, index-width aware. 8 elems/thread,
// 32 threads/row, 32768 rows. v clamped for fault safety.
// ---------------------------------------------------------------------------
__global__ __launch_bounds__(256) void k_gather(const void* __restrict__ x,
                                                const float* __restrict__ embed,
                                                const int* __restrict__ flag,
                                                ushort* __restrict__ out) {
    int chunk = blockIdx.x * 256 + threadIdx.x;
    int row = chunk >> 5;
    int c = chunk & 31;
    int v;
    if (flag[0]) {
        v = (int)((const uint*)x)[2 * row];  // int64 little-endian low word
    } else {
        v = ((const int*)x)[row];
    }
    v = min(max(v, 0), 49999);
    const float4* e = (const float4*)&embed[(size_t)v * 256 + (size_t)c * 8];
    float4 a = e[0], b = e[1];
    uint4 pv;
    pv.x = pack2(a.x, a.y);
    pv.y = pack2(a.z, a.w);
    pv.z = pack2(b.x, b.y);
    pv.w = pack2(b.z, b.w);
    *(uint4*)&out[(size_t)row * 256 + (size_t)c * 8] = pv;
}

// ---------------------------------------------------------------------------
// GEMM: C[M,N] = A[M,K](bf16) * W[N,K]^T(fp32, converted inline) + bias(fp32),
// optional exact GELU. 128x128 tile, 4 waves, 4x4 grid of 16x16x32 bf16 MFMAs.
// Epilogue writes bf16 to Cb and/or fp32 to Cf (whichever non-null;
// wave-uniform branch). M%128==0, K%32==0; N tail guarded.
// ---------------------------------------------------------------------------
__global__ __launch_bounds__(256) void k_gemm_bt(const ushort* __restrict__ A,
                                                 const float* __restrict__ Wf,
                                                 const float* __restrict__ bias,
                                                 ushort* __restrict__ Cb,
                                                 float* __restrict__ Cf,
                                                 int M, int N, int K, int gelu) {
    __shared__ __align__(16) ushort Al[128 * 32];
    __shared__ __align__(16) ushort Bl[128 * 32];
    int tid = threadIdx.x;
    int bm = blockIdx.x, bn = blockIdx.y;
    int wid = tid >> 6, lane = tid & 63;
    int ln = lane & 15, kq = lane >> 4;
    int wm = (wid & 1) * 64, wn = (wid >> 1) * 64;
    int rowA0 = bm * 128, rowB0 = bn * 128;

    f32x4 acc[4][4];
#pragma unroll
    for (int i = 0; i < 4; i++)
#pragma unroll
        for (int j = 0; j < 4; j++) acc[i][j] = (f32x4){0.f, 0.f, 0.f, 0.f};

    for (int kt = 0; kt < K; kt += 32) {
#pragma unroll
        for (int c = tid; c < 512; c += 256) {
            int r = c >> 2, c8 = (c & 3) * 8;
            *(uint4*)&Al[r * 32 + c8] =
                *(const uint4*)&A[(size_t)(rowA0 + r) * K + kt + c8];
            int nb = rowB0 + r;
            uint4 bv = {0u, 0u, 0u, 0u};
            if (nb < N) {
                const float4* wp = (const float4*)&Wf[(size_t)nb * K + kt + c8];
                float4 w0 = wp[0], w1 = wp[1];
                bv.x = pack2(w0.x, w0.y);
                bv.y = pack2(w0.z, w0.w);
                bv.z = pack2(w1.x, w1.y);
                bv.w = pack2(w1.z, w1.w);
            }
            *(uint4*)&Bl[r * 32 + c8] = bv;
        }
        __syncthreads();
        sh8 af[4], bfr[4];
#pragma unroll
        for (int i = 0; i < 4; i++)
            af[i] = *(const sh8*)&Al[(wm + i * 16 + ln) * 32 + kq * 8];
#pragma unroll
        for (int j = 0; j < 4; j++)
            bfr[j] = *(const sh8*)&Bl[(wn + j * 16 + ln) * 32 + kq * 8];
#pragma unroll
        for (int i = 0; i < 4; i++)
#pragma unroll
            for (int j = 0; j < 4; j++)
                acc[i][j] = __builtin_amdgcn_mfma_f32_16x16x32_bf16(
                    af[i], bfr[j], acc[i][j], 0, 0, 0);
        __syncthreads();
    }

#pragma unroll
    for (int i = 0; i < 4; i++)
#pragma unroll
        for (int j = 0; j < 4; j++) {
            int col = rowB0 + wn + j * 16 + ln;
            if (col >= N) continue;
            float bv = bias[col];
#pragma unroll
            for (int reg = 0; reg < 4; reg++) {
                int row = rowA0 + wm + i * 16 + kq * 4 + reg;
                float v = acc[i][j][reg] + bv;
                if (gelu) v = 0.5f * v * (1.0f + erff(v * 0.70710678118f));
                if (Cb) Cb[(size_t)row * N + col] = f2b(v);
                if (Cf) Cf[(size_t)row * N + col] = v;
            }
        }
}

// ---------------------------------------------------------------------------
// GRU recurrence, one layer — fp32 hidden state. grid = 128 blocks:
// b = idx&63, dir = idx>>6. Whh (fp32) in VGPRs: thread t owns rows
// r0..r0+2 (r0=(t>>1)*3) over k-half khalf=t&1. h state fp32 in LDS.
// In-place update of hb (bf16): o = h_new + resv; blocks touch disjoint
// (row-range, col-half) slices; read-before-write within one thread/step.
// ---------------------------------------------------------------------------
__global__ __launch_bounds__(256) void k_gru(const ushort* __restrict__ xp,
                                             const float* __restrict__ Whh_l,
                                             const float* __restrict__ bhh_l,
                                             ushort* __restrict__ hb) {
    __shared__ float hp2[768];
    __shared__ float hsh[128];

    int t = threadIdx.x;
    int b = blockIdx.x & 63;
    int dir = blockIdx.x >> 6;
    int khalf = t & 1;
    int r0 = (t >> 1) * 3;

    const float* Wd = Whh_l + (size_t)dir * 384 * 128;
    const float* bhh_d = bhh_l + dir * 384;

    float wf[3][64];
#pragma unroll
    for (int a = 0; a < 3; a++)
#pragma unroll
        for (int kk = 0; kk < 64; kk++)
            wf[a][kk] = Wd[(r0 + a) * 128 + khalf * 64 + kk];

    float bhr = 0.f, bhz = 0.f, bhn = 0.f, hstate = 0.f;
    if (t < 128) {
        bhr = bhh_d[t];
        bhz = bhh_d[128 + t];
        bhn = bhh_d[256 + t];
        hsh[t] = 0.f;
    }
    __syncthreads();

    const float* hk = hsh + khalf * 64;

    for (int s = 0; s < 512; ++s) {
        int ti = dir ? (511 - s) : s;
        size_t row = (size_t)b * 512 + ti;

        float xr = 0.f, xz = 0.f, xn = 0.f, resv = 0.f;
        if (t < 128) {
            const ushort* xpr = xp + row * 768 + dir * 384 + t;
            xr = b2f(xpr[0]);
            xz = b2f(xpr[128]);
            xn = b2f(xpr[256]);
            resv = b2f(hb[row * 256 + dir * 128 + t]);
        }

        float p0 = 0.f, p1 = 0.f, p2 = 0.f;
#pragma unroll
        for (int kk = 0; kk < 64; ++kk) {
            float hv = hk[kk];
            p0 = fmaf(wf[0][kk], hv, p0);
            p1 = fmaf(wf[1][kk], hv, p1);
            p2 = fmaf(wf[2][kk], hv, p2);
        }
        hp2[khalf * 384 + r0] = p0;
        hp2[khalf * 384 + r0 + 1] = p1;
        hp2[khalf * 384 + r0 + 2] = p2;
        __syncthreads();

        if (t < 128) {
            float hr = hp2[t] + hp2[384 + t] + bhr;
            float hz = hp2[128 + t] + hp2[512 + t] + bhz;
            float hn = hp2[256 + t] + hp2[640 + t] + bhn;
            float rg = sigmf(xr + hr);
            float zg = sigmf(xz + hz);
            float ng = tanh_cl(xn + rg * hn);
            hstate = (1.0f - zg) * ng + zg * hstate;
            hsh[t] = hstate;
            hb[row * 256 + dir * 128 + t] = f2b(hstate + resv);
        }
        __syncthreads();
    }
}

// ---------------------------------------------------------------------------
// Host launcher. fp32 inputs AND fp32 output; bf16 internally for MFMA.
// Scratch confined to 64 MiB:
//   [0, 48M)  xp (bf16 32768x768) — also hosts embA, then g (16 MiB each)
//   [48,64M)  hb (bf16 32768x256) — W1 out, GRU layers update in place
// x-width flag at hb[0], consumed by k_gather before W1 GEMM overwrites it.
// ---------------------------------------------------------------------------
extern "C" void kernel_launch(void* const* d_in, const int* in_sizes, int n_in,
                              void* d_out, int out_size, void* d_ws, size_t ws_size,
                              hipStream_t stream) {
    const void* x = d_in[0];
    const float* embed = (const float*)d_in[1];
    const float* W1 = (const float*)d_in[2];
    const float* b1 = (const float*)d_in[3];
    const float* Wih = (const float*)d_in[4];  // [2][2][384][256]
    const float* Whh = (const float*)d_in[5];  // [2][2][384][128]
    const float* bih = (const float*)d_in[6];  // [2][2][384]
    const float* bhh = (const float*)d_in[7];  // [2][2][384]
    const float* W2 = (const float*)d_in[8];
    const float* b2 = (const float*)d_in[9];
    const float* W3 = (const float*)d_in[10];
    const float* b3 = (const float*)d_in[11];

    char* ws = (char*)d_ws;
    ushort* xp = (ushort*)ws;                         // [0, 48M)
    ushort* hb = (ushort*)(ws + 32768ull * 768 * 2);  // [48M, 64M)
    ushort* embA = xp;  // 16 MiB slot, dead after W1 GEMM
    ushort* g = xp;     // reused after last GRU
    int* xflag = (int*)hb;  // transient; dead after k_gather

    // detect x index width, then gather + W1: hb = bf16(embA @ W1^T + b1)
    k_detx<<<1, 256, 0, stream>>>((const uint*)x, xflag);
    k_gather<<<4096, 256, 0, stream>>>(x, embed, xflag, embA);
    k_gemm_bt<<<dim3(256, 2), 256, 0, stream>>>(embA, W1, b1, hb, (float*)0,
                                                32768, 256, 256, 0);

    // layer 0: xp = hb @ Wih[0]^T + bih[0]; GRU updates hb in place
    k_gemm_bt<<<dim3(256, 6), 256, 0, stream>>>(hb, Wih, bih, xp, (float*)0,
                                                32768, 768, 256, 0);
    k_gru<<<128, 256, 0, stream>>>(xp, Whh, bhh, hb);

    // layer 1
    k_gemm_bt<<<dim3(256, 6), 256, 0, stream>>>(hb, Wih + 196608, bih + 768,
                                                xp, (float*)0, 32768, 768, 256, 0);
    k_gru<<<128, 256, 0, stream>>>(xp, Whh + 98304, bhh + 768, hb);

    // head: g = bf16(GELU(hb @ W2^T + b2)); d_out = fp32(g @ W3^T + b3)
    k_gemm_bt<<<dim3(256, 2), 256, 0, stream>>>(hb, W2, b2, g, (float*)0,
                                                32768, 256, 256, 1);
    k_gemm_bt<<<dim3(256, 1), 256, 0, stream>>>(g, W3, b3, (ushort*)0,
                                                (float*)d_out, 32768, 50, 256, 0);
}

// Round 10
// 1086.067 us; speedup vs baseline: 1.1317x; 1.1317x over previous
//
#include <hip/hip_runtime.h>

typedef unsigned int uint;
typedef unsigned short ushort;

typedef __attribute__((ext_vector_type(8))) short sh8;
typedef __attribute__((ext_vector_type(4))) float f32x4;

__device__ __forceinline__ ushort f2b(float f) {
    uint x = __float_as_uint(f);
    x += 0x7fffu + ((x >> 16) & 1u);
    return (ushort)(x >> 16);
}
__device__ __forceinline__ float b2f(ushort u) {
    return __uint_as_float(((uint)u) << 16);
}
__device__ __forceinline__ uint pack2(float a, float b) {
    return (uint)f2b(a) | ((uint)f2b(b) << 16);
}
__device__ __forceinline__ float sigmf(float x) {
    return 1.0f / (1.0f + __expf(-x));
}
__device__ __forceinline__ float tanh_cl(float y) {
    y = fminf(20.0f, fmaxf(-20.0f, y));
    float e = __expf(-2.0f * y);
    return (1.0f - e) / (1.0f + e);
}

// ---------------------------------------------------------------------------
// Index-width detector for x (robustness; x believed int32).
// ---------------------------------------------------------------------------
__global__ __launch_bounds__(256) void k_detx(const uint* __restrict__ xw,
                                              int* __restrict__ flag) {
    __shared__ int sh[256];
    int t = threadIdx.x;
    int c = 0;
    for (int i = t; i < 2048; i += 256) c += (xw[2 * i + 1] == 0u) ? 1 : 0;
    sh[t] = c;
    __syncthreads();
    if (t == 0) {
        int s = 0;
        for (int i = 0; i < 256; i++) s += sh[i];
        flag[0] = (s >= 1843) ? 1 : 0;  // >=90% zeros -> int64
    }
}

// ---------------------------------------------------------------------------
// Embedding gather, fp32 -> bf16, index-width aware.
// ---------------------------------------------------------------------------
__global__ __launch_bounds__(256) void k_gather(const void* __restrict__ x,
                                                const float* __restrict__ embed,
                                                const int* __restrict__ flag,
                                                ushort* __restrict__ out) {
    int chunk = blockIdx.x * 256 + threadIdx.x;
    int row = chunk >> 5;
    int c = chunk & 31;
    int v;
    if (flag[0]) {
        v = (int)((const uint*)x)[2 * row];
    } else {
        v = ((const int*)x)[row];
    }
    v = min(max(v, 0), 49999);
    const float4* e = (const float4*)&embed[(size_t)v * 256 + (size_t)c * 8];
    float4 a = e[0], b = e[1];
    uint4 pv;
    pv.x = pack2(a.x, a.y);
    pv.y = pack2(a.z, a.w);
    pv.z = pack2(b.x, b.y);
    pv.w = pack2(b.z, b.w);
    *(uint4*)&out[(size_t)row * 256 + (size_t)c * 8] = pv;
}

// ---------------------------------------------------------------------------
// GEMM (unchanged, verified): C = A(bf16) * W^T(fp32 inline->bf16) + bias,
// optional GELU; bf16 Cb and/or fp32 Cf outputs.
// ---------------------------------------------------------------------------
__global__ __launch_bounds__(256) void k_gemm_bt(const ushort* __restrict__ A,
                                                 const float* __restrict__ Wf,
                                                 const float* __restrict__ bias,
                                                 ushort* __restrict__ Cb,
                                                 float* __restrict__ Cf,
                                                 int M, int N, int K, int gelu) {
    __shared__ __align__(16) ushort Al[128 * 32];
    __shared__ __align__(16) ushort Bl[128 * 32];
    int tid = threadIdx.x;
    int bm = blockIdx.x, bn = blockIdx.y;
    int wid = tid >> 6, lane = tid & 63;
    int ln = lane & 15, kq = lane >> 4;
    int wm = (wid & 1) * 64, wn = (wid >> 1) * 64;
    int rowA0 = bm * 128, rowB0 = bn * 128;

    f32x4 acc[4][4];
#pragma unroll
    for (int i = 0; i < 4; i++)
#pragma unroll
        for (int j = 0; j < 4; j++) acc[i][j] = (f32x4){0.f, 0.f, 0.f, 0.f};

    for (int kt = 0; kt < K; kt += 32) {
#pragma unroll
        for (int c = tid; c < 512; c += 256) {
            int r = c >> 2, c8 = (c & 3) * 8;
            *(uint4*)&Al[r * 32 + c8] =
                *(const uint4*)&A[(size_t)(rowA0 + r) * K + kt + c8];
            int nb = rowB0 + r;
            uint4 bv = {0u, 0u, 0u, 0u};
            if (nb < N) {
                const float4* wp = (const float4*)&Wf[(size_t)nb * K + kt + c8];
                float4 w0 = wp[0], w1 = wp[1];
                bv.x = pack2(w0.x, w0.y);
                bv.y = pack2(w0.z, w0.w);
                bv.z = pack2(w1.x, w1.y);
                bv.w = pack2(w1.z, w1.w);
            }
            *(uint4*)&Bl[r * 32 + c8] = bv;
        }
        __syncthreads();
        sh8 af[4], bfr[4];
#pragma unroll
        for (int i = 0; i < 4; i++)
            af[i] = *(const sh8*)&Al[(wm + i * 16 + ln) * 32 + kq * 8];
#pragma unroll
        for (int j = 0; j < 4; j++)
            bfr[j] = *(const sh8*)&Bl[(wn + j * 16 + ln) * 32 + kq * 8];
#pragma unroll
        for (int i = 0; i < 4; i++)
#pragma unroll
            for (int j = 0; j < 4; j++)
                acc[i][j] = __builtin_amdgcn_mfma_f32_16x16x32_bf16(
                    af[i], bfr[j], acc[i][j], 0, 0, 0);
        __syncthreads();
    }

#pragma unroll
    for (int i = 0; i < 4; i++)
#pragma unroll
        for (int j = 0; j < 4; j++) {
            int col = rowB0 + wn + j * 16 + ln;
            if (col >= N) continue;
            float bv = bias[col];
#pragma unroll
            for (int reg = 0; reg < 4; reg++) {
                int row = rowA0 + wm + i * 16 + kq * 4 + reg;
                float v = acc[i][j][reg] + bv;
                if (gelu) v = 0.5f * v * (1.0f + erff(v * 0.70710678118f));
                if (Cb) Cb[(size_t)row * N + col] = f2b(v);
                if (Cf) Cf[(size_t)row * N + col] = v;
            }
        }
}

// ---------------------------------------------------------------------------
// GRU recurrence v2 — single barrier per step.
// grid = 128: b = idx&63, dir = idx>>6. 256 threads = 4 waves.
// Mapping: wave w, lane l: j = w*32 + (l&31) (hidden unit), khalf = l>>5.
// Thread computes rows {j, 128+j, 256+j} of Whh over k in [khalf*64, +64):
// 192 fp32 weights in regs. k-reduction via __shfl_xor(.,32) (same wave).
// h state double-buffered in LDS (read s&1, write 1-(s&1)) -> ONE barrier.
// xp/resv prefetched one step ahead. Outputs staged in double-buffered LDS
// (2 banks x 32 steps x 128 bf16), flushed as coalesced uint4 every 32 steps.
// In-place on hb: flush writes rows already processed; resv reads rows ahead.
// ---------------------------------------------------------------------------
__global__ __launch_bounds__(256, 1) void k_gru(const ushort* __restrict__ xp,
                                                const float* __restrict__ Whh_l,
                                                const float* __restrict__ bhh_l,
                                                ushort* __restrict__ hb) {
    __shared__ __align__(16) float hsh[2][128];
    __shared__ __align__(16) ushort obuf[2][32][128];

    int t = threadIdx.x;
    int b = blockIdx.x & 63;
    int dir = blockIdx.x >> 6;
    int w = t >> 6, l = t & 63;
    int jj = l & 31, khalf = l >> 5;
    int j = w * 32 + jj;

    const float* Wd = Whh_l + (size_t)dir * 384 * 128;
    const float* bhh_d = bhh_l + dir * 384;

    float wf[3][64];
#pragma unroll
    for (int a = 0; a < 3; a++)
#pragma unroll
        for (int kk = 0; kk < 64; kk++)
            wf[a][kk] = Wd[(size_t)(a * 128 + j) * 128 + khalf * 64 + kk];

    float bhr = 0.f, bhz = 0.f, bhn = 0.f, hstate = 0.f;
    ushort xr_n = 0, xz_n = 0, xn_n = 0, rv_n = 0;
    if (khalf == 0) {
        bhr = bhh_d[j];
        bhz = bhh_d[128 + j];
        bhn = bhh_d[256 + j];
        // prefetch step 0
        int ti0 = dir ? 511 : 0;
        size_t row0 = (size_t)b * 512 + ti0;
        const ushort* xpr = xp + row0 * 768 + dir * 384 + j;
        xr_n = xpr[0];
        xz_n = xpr[128];
        xn_n = xpr[256];
        rv_n = hb[row0 * 256 + dir * 128 + j];
    }
    if (t < 128) hsh[0][t] = 0.f;
    __syncthreads();

    for (int s = 0; s < 512; ++s) {
        // flush the completed obuf bank every 32 steps
        if ((s & 31) == 0 && s > 0) {
            int bank = 1 - ((s >> 5) & 1);
            int sb = s - 32;
#pragma unroll
            for (int q = 0; q < 2; q++) {
                int idx = t + q * 256;
                int st = idx >> 4;
                int c8 = (idx & 15) * 8;
                int ti = dir ? (511 - (sb + st)) : (sb + st);
                size_t row = (size_t)b * 512 + ti;
                *(uint4*)&hb[row * 256 + dir * 128 + c8] =
                    *(const uint4*)&obuf[bank][st][c8];
            }
        }

        float xr = b2f(xr_n), xz = b2f(xz_n), xn = b2f(xn_n), rv = b2f(rv_n);

        // prefetch step s+1 (loads complete under this step's compute)
        if (khalf == 0 && s + 1 < 512) {
            int ti1 = dir ? (511 - (s + 1)) : (s + 1);
            size_t row1 = (size_t)b * 512 + ti1;
            const ushort* xpr = xp + row1 * 768 + dir * 384 + j;
            xr_n = xpr[0];
            xz_n = xpr[128];
            xn_n = xpr[256];
            rv_n = hb[row1 * 256 + dir * 128 + j];
        }

        // matvec over this thread's k-half
        const float* hc = &hsh[s & 1][khalf * 64];
        float p0 = 0.f, p1 = 0.f, p2 = 0.f;
#pragma unroll
        for (int kk = 0; kk < 64; ++kk) {
            float hv = hc[kk];
            p0 = fmaf(wf[0][kk], hv, p0);
            p1 = fmaf(wf[1][kk], hv, p1);
            p2 = fmaf(wf[2][kk], hv, p2);
        }
        // k-half reduction within the wave
        p0 += __shfl_xor(p0, 32, 64);
        p1 += __shfl_xor(p1, 32, 64);
        p2 += __shfl_xor(p2, 32, 64);

        if (khalf == 0) {
            float rg = sigmf(xr + p0 + bhr);
            float zg = sigmf(xz + p1 + bhz);
            float ng = tanh_cl(xn + rg * (p2 + bhn));
            hstate = (1.0f - zg) * ng + zg * hstate;
            hsh[1 - (s & 1)][j] = hstate;
            obuf[(s >> 5) & 1][s & 31][j] = f2b(hstate + rv);
        }
        __syncthreads();
    }

    // final flush: steps 480..511 live in bank 1
    {
        int sb = 480;
#pragma unroll
        for (int q = 0; q < 2; q++) {
            int idx = t + q * 256;
            int st = idx >> 4;
            int c8 = (idx & 15) * 8;
            int ti = dir ? (511 - (sb + st)) : (sb + st);
            size_t row = (size_t)b * 512 + ti;
            *(uint4*)&hb[row * 256 + dir * 128 + c8] =
                *(const uint4*)&obuf[1][st][c8];
        }
    }
}

// ---------------------------------------------------------------------------
// Host launcher. fp32 inputs AND fp32 output; bf16 internally for MFMA.
// Scratch confined to 64 MiB:
//   [0, 48M)  xp (bf16 32768x768) — also hosts embA, then g (16 MiB each)
//   [48,64M)  hb (bf16 32768x256) — W1 out, GRU layers update in place
// ---------------------------------------------------------------------------
extern "C" void kernel_launch(void* const* d_in, const int* in_sizes, int n_in,
                              void* d_out, int out_size, void* d_ws, size_t ws_size,
                              hipStream_t stream) {
    const void* x = d_in[0];
    const float* embed = (const float*)d_in[1];
    const float* W1 = (const float*)d_in[2];
    const float* b1 = (const float*)d_in[3];
    const float* Wih = (const float*)d_in[4];  // [2][2][384][256]
    const float* Whh = (const float*)d_in[5];  // [2][2][384][128]
    const float* bih = (const float*)d_in[6];  // [2][2][384]
    const float* bhh = (const float*)d_in[7];  // [2][2][384]
    const float* W2 = (const float*)d_in[8];
    const float* b2 = (const float*)d_in[9];
    const float* W3 = (const float*)d_in[10];
    const float* b3 = (const float*)d_in[11];

    char* ws = (char*)d_ws;
    ushort* xp = (ushort*)ws;                         // [0, 48M)
    ushort* hb = (ushort*)(ws + 32768ull * 768 * 2);  // [48M, 64M)
    ushort* embA = xp;  // 16 MiB slot, dead after W1 GEMM
    ushort* g = xp;     // reused after last GRU
    int* xflag = (int*)hb;  // transient; dead after k_gather

    // detect x index width, then gather + W1: hb = bf16(embA @ W1^T + b1)
    k_detx<<<1, 256, 0, stream>>>((const uint*)x, xflag);
    k_gather<<<4096, 256, 0, stream>>>(x, embed, xflag, embA);
    k_gemm_bt<<<dim3(256, 2), 256, 0, stream>>>(embA, W1, b1, hb, (float*)0,
                                                32768, 256, 256, 0);

    // layer 0: xp = hb @ Wih[0]^T + bih[0]; GRU updates hb in place
    k_gemm_bt<<<dim3(256, 6), 256, 0, stream>>>(hb, Wih, bih, xp, (float*)0,
                                                32768, 768, 256, 0);
    k_gru<<<128, 256, 0, stream>>>(xp, Whh, bhh, hb);

    // layer 1
    k_gemm_bt<<<dim3(256, 6), 256, 0, stream>>>(hb, Wih + 196608, bih + 768,
                                                xp, (float*)0, 32768, 768, 256, 0);
    k_gru<<<128, 256, 0, stream>>>(xp, Whh + 98304, bhh + 768, hb);

    // head: g = bf16(GELU(hb @ W2^T + b2)); d_out = fp32(g @ W3^T + b3)
    k_gemm_bt<<<dim3(256, 2), 256, 0, stream>>>(hb, W2, b2, g, (float*)0,
                                                32768, 256, 256, 1);
    k_gemm_bt<<<dim3(256, 1), 256, 0, stream>>>(g, W3, b3, (ushort*)0,
                                                (float*)d_out, 32768, 50, 256, 0);
}